// Round 7
// baseline (91.302 us; speedup 1.0000x reference)
//
#include <hip/hip_runtime.h>
#include <hip/hip_fp16.h>
#include <math.h>

// Problem constants (from reference)
#define NUM_TREES 256
#define DEPTH 6
#define TREE_DIM 2
#define INPUT_DIM 256
#define BATCH 2048
#define NLEAF 64
#define NCOLS (NUM_TREES * DEPTH)    // 1536
#define KDIM INPUT_DIM

// Single-kernel tiling
#define BM 256        // batch rows per block (8 batch-blocks)
#define TPB 8         // trees per block (32 tree-groups)
#define BCOLS (TPB * DEPTH)          // 48 GEMM columns per block
#define BSLP 260      // Bsl stride in halfs: 130 words, col->bank step 2 -> <=2-way
#define FVP 53        // fv stride in floats: odd -> epilogue row reads 2-way (free)

typedef _Float16 half8 __attribute__((ext_vector_type(8)));
typedef float floatx4 __attribute__((ext_vector_type(4)));

// ---------------------------------------------------------------------------
// ONE kernel, ONE dispatch, no workspace:
//  Phase 1: per-block sparsemax of its 48 (tree,depth) columns (bisection,
//           12 iters, 6 cols/wave with 6-way ILP on the shuffle chains).
//           Selectors written straight into LDS in MFMA B-fragment order.
//           (x8 redundancy across batch-blocks ~1.5us wall - cheaper than the
//           kernel-A dispatch + gap + d_ws round-trip it replaces.)
//  Phase 2: GEMM with NO A-staging: wave w exclusively owns rows 32w..32w+31,
//           so A fragments load global->regs (coalesced float4, inline fp16
//           convert, register prefetch). B fully LDS-resident. Only 2
//           __syncthreads() in the whole kernel.
//  Phase 3: fv LDS transpose -> sparsemoid -> leaf DP (depth-5 folded) ->
//           response contraction -> out.
// LDS ~84 KB -> 1 block/CU (grid 256 = 1 per CU).
// ---------------------------------------------------------------------------
__global__ __launch_bounds__(512, 1) void odt_one_kernel(
    const float* __restrict__ inputs,   // [2048][256]
    const float* __restrict__ fsl,      // [256][1536]
    const float* __restrict__ thr,      // [256][6]  (flat = column index)
    const float* __restrict__ logt,     // [256][6]
    const float* __restrict__ resp,     // [256][2][64]
    float* __restrict__ out)            // [2048][512]
{
    __shared__ _Float16 Bsl[BCOLS][BSLP];            // 24.4 KB selectors, k-major
    __shared__ float    fv[BM][FVP];                 // 53.0 KB
    __shared__ float    respS[TPB * TREE_DIM * NLEAF]; // 4 KB
    __shared__ float    thrS[BCOLS], etS[BCOLS];

    const int tid  = threadIdx.x;
    const int lane = tid & 63;
    const int w    = tid >> 6;            // wave 0..7
    const int b0   = blockIdx.x * BM;     // 0..7
    const int treeBase = blockIdx.y * TPB;
    const int col0 = treeBase * DEPTH;    // global column of block col 0

    // Stage response (1024 floats = 512 x float2) and per-column thr/exp(-logt).
    ((float2*)respS)[tid] = ((const float2*)(resp + treeBase * TREE_DIM * NLEAF))[tid];
    if (tid < BCOLS) {
        thrS[tid] = thr[col0 + tid];      // thr flat layout == column order
        etS[tid]  = __expf(-logt[col0 + tid]);
    }

    // ---- Phase 1: sparsemax, wave w handles cols w*6..w*6+5 (tree treeBase+w).
    {
        float x[6][4];
        const float* base = fsl + col0 + w * 6;
#pragma unroll
        for (int j = 0; j < 4; ++j) {
            const float* r = base + (j * 64 + lane) * NCOLS;
            const float2 v0 = *(const float2*)(r);
            const float2 v1 = *(const float2*)(r + 2);
            const float2 v2 = *(const float2*)(r + 4);
            x[0][j] = v0.x; x[1][j] = v0.y; x[2][j] = v1.x;
            x[3][j] = v1.y; x[4][j] = v2.x; x[5][j] = v2.y;
        }
        float lo[6], hi[6];
#pragma unroll
        for (int c = 0; c < 6; ++c) {
            float m = fmaxf(fmaxf(x[c][0], x[c][1]), fmaxf(x[c][2], x[c][3]));
#pragma unroll
            for (int off = 32; off > 0; off >>= 1)
                m = fmaxf(m, __shfl_xor(m, off));
            hi[c] = m; lo[c] = m - 1.0f;
        }
        for (int it = 0; it < 12; ++it) {      // tau err 2.4e-4 << fp16 GEMM noise
            float s[6], mid[6];
#pragma unroll
            for (int c = 0; c < 6; ++c) {
                mid[c] = 0.5f * (lo[c] + hi[c]);
                s[c] = fmaxf(x[c][0] - mid[c], 0.f) + fmaxf(x[c][1] - mid[c], 0.f)
                     + fmaxf(x[c][2] - mid[c], 0.f) + fmaxf(x[c][3] - mid[c], 0.f);
            }
#pragma unroll
            for (int off = 32; off > 0; off >>= 1)   // 6-way ILP butterfly
#pragma unroll
                for (int c = 0; c < 6; ++c)
                    s[c] += __shfl_xor(s[c], off);
#pragma unroll
            for (int c = 0; c < 6; ++c) {
                if (s[c] > 1.0f) lo[c] = mid[c]; else hi[c] = mid[c];
            }
        }
#pragma unroll
        for (int c = 0; c < 6; ++c) {
            const float tau = 0.5f * (lo[c] + hi[c]);
#pragma unroll
            for (int j = 0; j < 4; ++j)
                Bsl[w * 6 + c][j * 64 + lane] = (_Float16)fmaxf(x[c][j] - tau, 0.f);
        }
    }
    __syncthreads();   // Bsl + respS + thrS/etS visible

    // ---- Phase 2: GEMM. Wave w -> rows b0+32w..+31, all 48 cols.
    const int l16 = lane & 15, quad = lane >> 4;
    floatx4 acc[2][3];
#pragma unroll
    for (int mt = 0; mt < 2; ++mt)
#pragma unroll
        for (int nt = 0; nt < 3; ++nt)
            acc[mt][nt] = (floatx4){0.f, 0.f, 0.f, 0.f};

    // A fragment source: row = b0 + 32w + 16mt + l16, k = k0 + quad*8 + 0..7.
    const float* aBase = inputs + (b0 + 32 * w + l16) * KDIM + quad * 8;
    float4 p[2][2];
#pragma unroll
    for (int mt = 0; mt < 2; ++mt) {
        p[mt][0] = *(const float4*)(aBase + mt * 16 * KDIM);
        p[mt][1] = *(const float4*)(aBase + mt * 16 * KDIM + 4);
    }

    for (int k0 = 0; k0 < KDIM; k0 += 32) {
        half8 af[2];
#pragma unroll
        for (int mt = 0; mt < 2; ++mt) {
            af[mt][0] = (_Float16)p[mt][0].x; af[mt][1] = (_Float16)p[mt][0].y;
            af[mt][2] = (_Float16)p[mt][0].z; af[mt][3] = (_Float16)p[mt][0].w;
            af[mt][4] = (_Float16)p[mt][1].x; af[mt][5] = (_Float16)p[mt][1].y;
            af[mt][6] = (_Float16)p[mt][1].z; af[mt][7] = (_Float16)p[mt][1].w;
        }
        if (k0 + 32 < KDIM) {   // register prefetch of next K-step
#pragma unroll
            for (int mt = 0; mt < 2; ++mt) {
                p[mt][0] = *(const float4*)(aBase + mt * 16 * KDIM + k0 + 32);
                p[mt][1] = *(const float4*)(aBase + mt * 16 * KDIM + k0 + 36);
            }
        }
        const half8 bf0 = *(const half8*)&Bsl[l16][k0 + quad * 8];
        const half8 bf1 = *(const half8*)&Bsl[16 + l16][k0 + quad * 8];
        const half8 bf2 = *(const half8*)&Bsl[32 + l16][k0 + quad * 8];
        acc[0][0] = __builtin_amdgcn_mfma_f32_16x16x32_f16(af[0], bf0, acc[0][0], 0, 0, 0);
        acc[0][1] = __builtin_amdgcn_mfma_f32_16x16x32_f16(af[0], bf1, acc[0][1], 0, 0, 0);
        acc[0][2] = __builtin_amdgcn_mfma_f32_16x16x32_f16(af[0], bf2, acc[0][2], 0, 0, 0);
        acc[1][0] = __builtin_amdgcn_mfma_f32_16x16x32_f16(af[1], bf0, acc[1][0], 0, 0, 0);
        acc[1][1] = __builtin_amdgcn_mfma_f32_16x16x32_f16(af[1], bf1, acc[1][1], 0, 0, 0);
        acc[1][2] = __builtin_amdgcn_mfma_f32_16x16x32_f16(af[1], bf2, acc[1][2], 0, 0, 0);
    }

    // C/D layout (m89-verified): col = lane&15, row = quad*4 + reg.
#pragma unroll
    for (int mt = 0; mt < 2; ++mt)
#pragma unroll
        for (int nt = 0; nt < 3; ++nt)
#pragma unroll
            for (int r = 0; r < 4; ++r)
                fv[32 * w + 16 * mt + 4 * quad + r][16 * nt + l16] = acc[mt][nt][r];
    __syncthreads();

    // ---- Phase 3: 2048 (row,tree) pairs, 4 per thread; tl wave-uniform.
#pragma unroll
    for (int pp = 0; pp < 4; ++pp) {
        const int idx = tid + 512 * pp;
        const int row = idx & 255;
        const int tl  = idx >> 8;            // 0..7
        const float* f = &fv[row][tl * 6];

        float sd[DEPTH];
#pragma unroll
        for (int d = 0; d < DEPTH; ++d) {
            const float tlg = (f[d] - thrS[tl * 6 + d]) * etS[tl * 6 + d];
            sd[d] = fminf(fmaxf(0.5f + 0.5f * tlg, 0.0f), 1.0f);
        }
        // DP over depths 0..4 (32 leaves); depth-5 factor folds into the
        // contraction. Leaf bit d == 1 -> factor (1 - sd[d]).
        float wv[NLEAF / 2];
        wv[0] = 1.0f;
#pragma unroll
        for (int d = 0; d < 5; ++d) {
            const int sz = 1 << d;
#pragma unroll
            for (int c2 = 0; c2 < 16; ++c2) {
                if (c2 < sz) {
                    const float t = wv[c2];
                    wv[c2]      = t * sd[d];
                    wv[c2 + sz] = t * (1.0f - sd[d]);
                }
            }
        }
        const float* r0 = &respS[tl * TREE_DIM * NLEAF];
        float a0 = 0.f, c0 = 0.f, a1 = 0.f, c1 = 0.f;
#pragma unroll
        for (int c2 = 0; c2 < 32; ++c2) {
            a0 = fmaf(wv[c2], r0[c2], a0);
            c0 = fmaf(wv[c2], r0[c2 + 32], c0);
            a1 = fmaf(wv[c2], r0[NLEAF + c2], a1);
            c1 = fmaf(wv[c2], r0[NLEAF + c2 + 32], c1);
        }
        const float s5 = sd[5], s5b = 1.0f - sd[5];
        float2 o;
        o.x = s5 * a0 + s5b * c0;
        o.y = s5 * a1 + s5b * c1;
        *(float2*)(out + (b0 + row) * (NUM_TREES * TREE_DIM)
                   + (treeBase + tl) * TREE_DIM) = o;
    }
}

// ---------------------------------------------------------------------------
extern "C" void kernel_launch(void* const* d_in, const int* in_sizes, int n_in,
                              void* d_out, int out_size, void* d_ws, size_t ws_size,
                              hipStream_t stream) {
    const float* inputs = (const float*)d_in[0];  // [2048][256]
    const float* fsl    = (const float*)d_in[1];  // [256][256][6]
    const float* thr    = (const float*)d_in[2];  // [256][6]
    const float* logt   = (const float*)d_in[3];  // [256][6]
    const float* resp   = (const float*)d_in[4];  // [256][2][64]
    float* out = (float*)d_out;                   // [2048][512]
    (void)d_ws; (void)ws_size;                    // no workspace needed

    hipLaunchKernelGGL(odt_one_kernel, dim3(BATCH / BM, NUM_TREES / TPB), dim3(512),
                       0, stream, inputs, fsl, thr, logt, resp, out);
}